// Round 3
// baseline (890.073 us; speedup 1.0000x reference)
//
#include <hip/hip_runtime.h>
#include <math.h>

typedef unsigned short ushort_t;
typedef __attribute__((ext_vector_type(8))) short short8;
typedef __attribute__((ext_vector_type(4))) float floatx4;

#define VMCNT(n) asm volatile("s_waitcnt vmcnt(" #n ")" ::: "memory")

// fp32 -> bf16 round-to-nearest-even, bit-level (no NaN inputs here)
__device__ inline ushort_t f2bf(float x) {
    union { float f; unsigned int u; } c; c.f = x;
    unsigned int r = (c.u + 0x7fffu + ((c.u >> 16) & 1u)) >> 16;
    return (ushort_t)r;
}

// async global->LDS, 16 B per lane; lds base must be wave-uniform
__device__ __forceinline__ void glds16(const ushort_t* g, ushort_t* l) {
    __builtin_amdgcn_global_load_lds(
        (const __attribute__((address_space(1))) unsigned int*)g,
        (__attribute__((address_space(3))) unsigned int*)l,
        16, 0, 0);
}

// bank-conflict swizzle: XOR 16B-slot bits (4:6) with bits (7:9).
// Involution; valid for 64B-row tiles (pair-of-rows key) and 128B-row tiles.
__device__ __forceinline__ unsigned swzo(unsigned off) {
    return off ^ ((off >> 3) & 0x70u);
}

// ---------------------------------------------------------------------------
// Kernel 0: W [1024,3072] fp32  ->  W_t [3072,1024] bf16  (unchanged, passing)
__global__ __launch_bounds__(256)
void wt_kernel(const float* __restrict__ W, ushort_t* __restrict__ Wt)
{
    __shared__ float tile[64][65];
    const int k0 = blockIdx.x * 64;
    const int n0 = blockIdx.y * 64;
    const int tid = threadIdx.x;
    #pragma unroll
    for (int ii = 0; ii < 16; ++ii) {
        int idx = ii * 256 + tid;
        int r = idx >> 6, c = idx & 63;
        tile[r][c] = W[(size_t)(k0 + r) * 3072 + n0 + c];
    }
    __syncthreads();
    #pragma unroll
    for (int ii = 0; ii < 16; ++ii) {
        int idx = ii * 256 + tid;
        int r = idx >> 6, c = idx & 63;
        Wt[(size_t)(n0 + r) * 1024 + k0 + c] = f2bf(tile[c][r]);
    }
}

// ---------------------------------------------------------------------------
// Kernel 0b: x [B,S,D] fp32 -> xb bf16 (prepass so qkv can glds16 both sides)
__global__ __launch_bounds__(256)
void xcvt(const float* __restrict__ x, ushort_t* __restrict__ xb)
{
    const int i = (blockIdx.x * 256 + threadIdx.x) * 8;   // exact: 16777216 elems
    float4 f0 = *(const float4*)(x + i);
    float4 f1 = *(const float4*)(x + i + 4);
    ushort_t tmp[8] __attribute__((aligned(16)));
    tmp[0]=f2bf(f0.x); tmp[1]=f2bf(f0.y); tmp[2]=f2bf(f0.z); tmp[3]=f2bf(f0.w);
    tmp[4]=f2bf(f1.x); tmp[5]=f2bf(f1.y); tmp[6]=f2bf(f1.z); tmp[7]=f2bf(f1.w);
    *(uint4*)(xb + i) = *(const uint4*)tmp;
}

// ---------------------------------------------------------------------------
// Kernel 1 (fallback, unchanged): qkv projection, reg-staged fp32 A
__global__ __launch_bounds__(256)
void qkv_mfma(const float* __restrict__ x, const ushort_t* __restrict__ Wt,
              const float* __restrict__ bias,
              ushort_t* __restrict__ q, ushort_t* __restrict__ k,
              ushort_t* __restrict__ vt)
{
    __shared__ ushort_t As[128][72];
    __shared__ ushort_t Bs[128][72];
    const int tid = threadIdx.x;
    const int w = tid >> 6, lane = tid & 63;
    const int m = lane & 15, quad = lane >> 4;
    const int col0 = blockIdx.x * 128;
    const int r0   = blockIdx.y * 128;

    floatx4 o[2][8];
    #pragma unroll
    for (int rf = 0; rf < 2; ++rf)
        #pragma unroll
        for (int nf = 0; nf < 8; ++nf)
            o[rf][nf] = (floatx4){0.f, 0.f, 0.f, 0.f};

    for (int kc = 0; kc < 16; ++kc) {
        const int kdim = kc * 64;
        __syncthreads();
        #pragma unroll
        for (int ii = 0; ii < 4; ++ii) {
            int lin = ii * 256 + tid;
            int row = lin >> 3, seg = lin & 7;
            const float* src = x + (size_t)(r0 + row) * 1024 + kdim + seg * 8;
            float4 f0 = *(const float4*)src;
            float4 f1 = *(const float4*)(src + 4);
            ushort_t tmp[8] __attribute__((aligned(16)));
            tmp[0]=f2bf(f0.x); tmp[1]=f2bf(f0.y); tmp[2]=f2bf(f0.z); tmp[3]=f2bf(f0.w);
            tmp[4]=f2bf(f1.x); tmp[5]=f2bf(f1.y); tmp[6]=f2bf(f1.z); tmp[7]=f2bf(f1.w);
            *(uint4*)&As[row][seg * 8] = *(const uint4*)tmp;
        }
        #pragma unroll
        for (int ii = 0; ii < 4; ++ii) {
            int lin = ii * 256 + tid;
            int row = lin >> 3, seg = lin & 7;
            const ushort_t* src = Wt + (size_t)(col0 + row) * 1024 + kdim + seg * 8;
            *(uint4*)&Bs[row][seg * 8] = *(const uint4*)src;
        }
        __syncthreads();
        #pragma unroll
        for (int kk = 0; kk < 2; ++kk) {
            short8 af[2];
            #pragma unroll
            for (int rf = 0; rf < 2; ++rf)
                af[rf] = *(const short8*)&As[w * 32 + rf * 16 + m][kk * 32 + quad * 8];
            #pragma unroll
            for (int nf = 0; nf < 8; ++nf) {
                short8 bf = *(const short8*)&Bs[nf * 16 + m][kk * 32 + quad * 8];
                #pragma unroll
                for (int rf = 0; rf < 2; ++rf)
                    o[rf][nf] = __builtin_amdgcn_mfma_f32_16x16x32_bf16(af[rf], bf, o[rf][nf], 0, 0, 0);
            }
        }
    }

    const int which = col0 >> 10;
    const int dbase = col0 & 1023;
    float bias_v[8];
    #pragma unroll
    for (int nf = 0; nf < 8; ++nf) bias_v[nf] = bias[col0 + nf * 16 + m];

    #pragma unroll
    for (int rf = 0; rf < 2; ++rf) {
        #pragma unroll
        for (int e = 0; e < 4; ++e) {
            const int g = r0 + w * 32 + rf * 16 + quad * 4 + e;
            #pragma unroll
            for (int nf = 0; nf < 8; ++nf) {
                const int c = dbase + nf * 16 + m;
                float val = o[rf][nf][e] + bias_v[nf];
                if (which == 0) {
                    q[(size_t)g * 1024 + c] = f2bf(val * 0.03125f);
                } else if (which == 1) {
                    k[(size_t)g * 1024 + c] = f2bf(val);
                } else {
                    vt[(size_t)(g >> 12) * 4194304 + (size_t)c * 4096 + (g & 4095)] = f2bf(val);
                }
            }
        }
    }
}

// ---------------------------------------------------------------------------
// Kernel 1 v3: qkv projection, m97-style; NEW: the V-third epilogue stages the
// output tile in LDS (two 64-col passes) and stores vt with coalesced 16B
// column runs instead of 2B stride-8KB scatters.
__global__ __launch_bounds__(256)
void qkv_mfma2(const ushort_t* __restrict__ xb, const ushort_t* __restrict__ Wt,
               const float* __restrict__ bias,
               ushort_t* __restrict__ q, ushort_t* __restrict__ k,
               ushort_t* __restrict__ vt)
{
    __shared__ __align__(1024) ushort_t smem[2 * 128 * 64];
    ushort_t (*As)[64] = (ushort_t (*)[64])smem;
    ushort_t (*Bs)[64] = (ushort_t (*)[64])(smem + 128 * 64);
    const int tid = threadIdx.x;
    const int w = tid >> 6, lane = tid & 63;
    const int m = lane & 15, quad = lane >> 4;
    const int lx = lane ^ ((lane >> 3) & 7);
    const int sr = lx >> 3, sc = (lx & 7) * 8;
    const int col0 = blockIdx.x * 128;
    const int r0   = blockIdx.y * 128;

    floatx4 o[2][8];
    #pragma unroll
    for (int rf = 0; rf < 2; ++rf)
        #pragma unroll
        for (int nf = 0; nf < 8; ++nf)
            o[rf][nf] = (floatx4){0.f, 0.f, 0.f, 0.f};

    for (int kc = 0; kc < 16; ++kc) {
        const int kdim = kc * 64;
        __syncthreads();
        #pragma unroll
        for (int ii = 0; ii < 4; ++ii) {
            glds16(xb + (size_t)(r0 + w * 32 + ii * 8 + sr) * 1024 + kdim + sc,
                   &As[w * 32 + ii * 8][0]);
            glds16(Wt + (size_t)(col0 + w * 32 + ii * 8 + sr) * 1024 + kdim + sc,
                   &Bs[w * 32 + ii * 8][0]);
        }
        __syncthreads();
        #pragma unroll
        for (int kk = 0; kk < 2; ++kk) {
            short8 af[2];
            #pragma unroll
            for (int rf = 0; rf < 2; ++rf)
                af[rf] = *(const short8*)((const char*)As +
                          swzo((unsigned)((w * 32 + rf * 16 + m) * 128 + kk * 64 + quad * 16)));
            #pragma unroll
            for (int nf = 0; nf < 8; ++nf) {
                short8 bf = *(const short8*)((const char*)Bs +
                          swzo((unsigned)((nf * 16 + m) * 128 + kk * 64 + quad * 16)));
                #pragma unroll
                for (int rf = 0; rf < 2; ++rf)
                    o[rf][nf] = __builtin_amdgcn_mfma_f32_16x16x32_bf16(af[rf], bf, o[rf][nf], 0, 0, 0);
            }
        }
    }

    const int which = col0 >> 10;
    const int dbase = col0 & 1023;
    float bias_v[8];
    #pragma unroll
    for (int nf = 0; nf < 8; ++nf) bias_v[nf] = bias[col0 + nf * 16 + m];

    if (which == 2) {
        // transpose-store vt: stage [64 cols][128 rows] in LDS, store 16B runs
        const size_t voffb = (size_t)(r0 >> 12) * 4194304;
        const int grow0 = r0 & 4095;
        ushort_t (*T)[136] = (ushort_t (*)[136])smem;
        #pragma unroll
        for (int p = 0; p < 2; ++p) {
            __syncthreads();   // T region free (MFMA reads / prev-pass stores done)
            #pragma unroll
            for (int rf = 0; rf < 2; ++rf)
                #pragma unroll
                for (int e = 0; e < 4; ++e) {
                    const int row = w * 32 + rf * 16 + quad * 4 + e;
                    #pragma unroll
                    for (int nn = 0; nn < 4; ++nn) {
                        const int nf = p * 4 + nn;
                        T[nn * 16 + m][row] = f2bf(o[rf][nf][e] + bias_v[nf]);
                    }
                }
            __syncthreads();
            #pragma unroll
            for (int ii = 0; ii < 4; ++ii) {
                int idx = ii * 256 + tid;
                int c = idx >> 4, seg = idx & 15;
                *(uint4*)&vt[voffb + (size_t)(dbase + p * 64 + c) * 4096 + grow0 + seg * 8]
                    = *(const uint4*)&T[c][seg * 8];
            }
        }
    } else {
        #pragma unroll
        for (int rf = 0; rf < 2; ++rf) {
            #pragma unroll
            for (int e = 0; e < 4; ++e) {
                const int g = r0 + w * 32 + rf * 16 + quad * 4 + e;
                #pragma unroll
                for (int nf = 0; nf < 8; ++nf) {
                    const int c = dbase + nf * 16 + m;
                    float val = o[rf][nf][e] + bias_v[nf];
                    if (which == 0) {
                        q[(size_t)g * 1024 + c] = f2bf(val * 0.03125f);
                    } else {
                        k[(size_t)g * 1024 + c] = f2bf(val);
                    }
                }
            }
        }
    }
}

// ---------------------------------------------------------------------------
// Kernel 2 v7: fused attention = v6 + counted-vmcnt PV (T3/T4 on both phases).
//  S phase : Ks triple-buffered (prefetch pre-barrier, VMCNT(2)); Qs DOUBLE-
//            buffered with prefetch issued POST-barrier (WAR-safe: target
//            buffer's readers all passed the preceding barrier).
//  exp     : Pls now [128][256] (64 KB) with row-XOR swizzle key (row&7)<<4 on
//            16B slots — ap reads 2-way (free); frees 3.5 KB for Vs[3].
//  PV phase: Vs TRIPLE-buffered, prefetch pre-barrier, VMCNT(4) — V loads
//            stay in flight across barriers. V(0) issued before the exp phase
//            so its latency hides under ~600 cyc of VALU.
// LDS = Qs 16K + Ks 48K (region aliased by Pls 64K + redL) + Vs 96K = 160 KiB.
__global__ __launch_bounds__(512, 2)
void fused_attn(const ushort_t* __restrict__ q, const ushort_t* __restrict__ kb_,
                const ushort_t* __restrict__ vt, float* __restrict__ out)
{
    // LDS map (163840 B total = 160 KiB exactly):
    //   [0,16384)        Qs[2][128][32]   -- aliased by Pls
    //   [16384,65536)    Ks[3][256][32]   -- aliased by Pls
    //   [0,65536)        Pls[128][256]    row-XOR swizzled
    //   [0,2048)         redL[128][4]     (finalize only)
    //   [65536,163840)   Vs[3][512][32]
    __shared__ __align__(1024) unsigned char lds[163840];
    ushort_t (*Qs)[128][32] = (ushort_t(*)[128][32])(lds);
    ushort_t (*Ks)[256][32] = (ushort_t(*)[256][32])(lds + 16384);
    ushort_t (*Vs)[512][32] = (ushort_t(*)[512][32])(lds + 65536);
    float    (*redL)[4]     = (float(*)[4])(lds);

    const int tid  = threadIdx.x;
    const int w    = tid >> 6, lane = tid & 63;
    const int m    = lane & 15, quad = lane >> 4;
    const int wr   = w & 1, wc = w >> 1;
    // swizzled staging source lane: 1024B region = 16 rows x 64 B
    const int lx   = lane ^ ((lane >> 3) & 7);
    const int lr   = lx >> 2, lc = (lx & 3) * 8;
    const int n0x  = blockIdx.x * 512;
    const int r0   = blockIdx.y * 128;
    const int b    = blockIdx.z;
    const size_t qoff = (size_t)b * 4096 * 1024;
    const size_t voff = (size_t)b * 4194304;

    // hoisted swizzled read offsets (bytes, within a tile)
    unsigned qof[4], kof[4], vof[8];
    #pragma unroll
    for (int i = 0; i < 4; ++i)
        qof[i] = swzo((unsigned)((wr * 64 + i * 16 + m) * 64 + quad * 16));
    #pragma unroll
    for (int j = 0; j < 4; ++j)
        kof[j] = swzo((unsigned)((wc * 64 + j * 16 + m) * 64 + quad * 16));
    #pragma unroll
    for (int j = 0; j < 8; ++j)
        vof[j] = swzo((unsigned)((wc * 128 + j * 16 + m) * 64 + quad * 16));

    // Pls read bases: byte = row*512 + ((vc*64 + quad*16) ^ ((row&7)<<4)).
    // Fields are disjoint bits -> split key: bits4-5 fold into quad part,
    // bit6 folds into the vc part as (vc ^ flip)*64.
    unsigned pbase[4], pflip[4];
    #pragma unroll
    for (int i = 0; i < 4; ++i) {
        const int prow = wr * 64 + i * 16 + m;
        pbase[i] = ((unsigned)prow << 9) + (((unsigned)quad << 4) ^ (((unsigned)(prow & 3)) << 4));
        pflip[i] = ((unsigned)((prow >> 2) & 1)) << 6;
    }

    // hoisted glds source row bases
    const ushort_t* qsrc  = q   + qoff + (size_t)(r0 + w * 16 + lr) * 1024 + lc;
    const ushort_t* ksrc0 = kb_ + qoff + (size_t)(w * 32 + lr) * 1024 + lc;
    const ushort_t* ksrc1 = kb_ + qoff + (size_t)(w * 32 + 16 + lr) * 1024 + lc;

    floatx4 o[4][8];
    #pragma unroll
    for (int i = 0; i < 4; ++i)
        #pragma unroll
        for (int j = 0; j < 8; ++j)
            o[i][j] = (floatx4){0.f, 0.f, 0.f, 0.f};
    float lsum[4][4] = {};

    for (int kt = 0; kt < 16; ++kt) {
        const int kbase = kt * 256;

        floatx4 s[4][4];
        #pragma unroll
        for (int i = 0; i < 4; ++i)
            #pragma unroll
            for (int j = 0; j < 4; ++j)
                s[i][j] = (floatx4){0.f, 0.f, 0.f, 0.f};

        // ---- S = Q K^T, kc = 32-dim chunks; Ks triple, Qs double ----
        glds16(ksrc0 + (size_t)kbase * 1024, &Ks[0][w * 32][0]);
        glds16(ksrc1 + (size_t)kbase * 1024, &Ks[0][w * 32 + 16][0]);
        glds16(qsrc,                         &Qs[0][w * 16][0]);
        {
            int curK = 0;
            for (int kc = 0; kc < 32; ++kc) {
                const int nxtK = (curK == 2) ? 0 : curK + 1;
                if (kc < 31) {
                    const int kd = (kc + 1) * 32;
                    glds16(ksrc0 + (size_t)kbase * 1024 + kd, &Ks[nxtK][w * 32][0]);
                    glds16(ksrc1 + (size_t)kbase * 1024 + kd, &Ks[nxtK][w * 32 + 16][0]);
                    VMCNT(2);   // K(kc)+Q(kc) done; K(kc+1) stays in flight
                } else {
                    VMCNT(0);
                }
                __builtin_amdgcn_s_barrier();
                __builtin_amdgcn_sched_barrier(0);
                if (kc < 31) {
                    // post-barrier Q prefetch: Qs[(kc+1)&1]'s readers (step kc-1)
                    // all passed the barrier above -> WAR-safe with 2 buffers
                    glds16(qsrc + (kc + 1) * 32, &Qs[(kc + 1) & 1][w * 16][0]);
                }
                short8 af[4], bf[4];
                #pragma unroll
                for (int i = 0; i < 4; ++i)
                    af[i] = *(const short8*)((const char*)Qs[kc & 1] + qof[i]);
                #pragma unroll
                for (int j = 0; j < 4; ++j)
                    bf[j] = *(const short8*)((const char*)Ks[curK] + kof[j]);
                __builtin_amdgcn_s_setprio(1);
                #pragma unroll
                for (int i = 0; i < 4; ++i)
                    #pragma unroll
                    for (int j = 0; j < 4; ++j)
                        s[i][j] = __builtin_amdgcn_mfma_f32_16x16x32_bf16(af[i], bf[j], s[i][j], 0, 0, 0);
                __builtin_amdgcn_s_setprio(0);
                curK = nxtK;
            }
        }
        __syncthreads();   // all waves done reading Qs/Ks before Pls overwrite

        // ---- V(0) prefetch: latency hides under the exp phase ----
        #pragma unroll
        for (int i = 0; i < 4; ++i)
            glds16(vt + voff + (size_t)(n0x + w * 64 + i * 16 + lr) * 4096 + kbase + lc,
                   &Vs[0][w * 64 + i * 16][0]);

        // ---- exp -> Pls (swizzled [128][256], aliases Qs/Ks) ----
        #pragma unroll
        for (int i = 0; i < 4; ++i)
            #pragma unroll
            for (int j = 0; j < 4; ++j)
                #pragma unroll
                for (int e = 0; e < 4; ++e) {
                    float pv = __expf(s[i][j][e]);
                    lsum[i][e] += pv;
                    const int prow = wr * 64 + i * 16 + quad * 4 + e;
                    const unsigned pcolb = (unsigned)((wc * 64 + j * 16 + m) << 1);
                    *(ushort_t*)(lds + ((unsigned)prow << 9) +
                                 (pcolb ^ (((unsigned)(prow & 7)) << 4))) = f2bf(pv);
                }
        __syncthreads();   // Pls visible; V(0) drained here (window = exp phase)

        // ---- O += P V, vc = 32-key chunks; Vs triple, counted vmcnt ----
        {
            int curV = 0;
            for (int vc = 0; vc < 8; ++vc) {
                const int nxtV = (curV == 2) ? 0 : curV + 1;
                if (vc < 7) {
                    const int kd = kbase + (vc + 1) * 32;
                    #pragma unroll
                    for (int i = 0; i < 4; ++i)
                        glds16(vt + voff + (size_t)(n0x + w * 64 + i * 16 + lr) * 4096 + kd + lc,
                               &Vs[nxtV][w * 64 + i * 16][0]);
                    VMCNT(4);   // V(vc) done; V(vc+1) stays in flight
                } else {
                    VMCNT(0);
                }
                __builtin_amdgcn_s_barrier();
                __builtin_amdgcn_sched_barrier(0);
                short8 ap[4], bv[8];
                #pragma unroll
                for (int i = 0; i < 4; ++i)
                    ap[i] = *(const short8*)(lds + pbase[i] + (((unsigned)vc << 6) ^ pflip[i]));
                #pragma unroll
                for (int j = 0; j < 8; ++j)
                    bv[j] = *(const short8*)((const char*)Vs[curV] + vof[j]);
                __builtin_amdgcn_s_setprio(1);
                #pragma unroll
                for (int i = 0; i < 4; ++i)
                    #pragma unroll
                    for (int j = 0; j < 8; ++j)
                        o[i][j] = __builtin_amdgcn_mfma_f32_16x16x32_bf16(ap[i], bv[j], o[i][j], 0, 0, 0);
                __builtin_amdgcn_s_setprio(0);
                curV = nxtV;
            }
        }
        __syncthreads();   // all waves done reading Pls/Vs before next kt staging
    }

    // ---- finalize: reduce lsum over the 16 m-lanes, combine col-quarters ----
    #pragma unroll
    for (int i = 0; i < 4; ++i)
        #pragma unroll
        for (int e = 0; e < 4; ++e) {
            float l = lsum[i][e];
            l += __shfl_xor(l, 1);
            l += __shfl_xor(l, 2);
            l += __shfl_xor(l, 4);
            l += __shfl_xor(l, 8);
            if (m == 0) redL[wr * 64 + i * 16 + quad * 4 + e][wc] = l;
        }
    __syncthreads();
    #pragma unroll
    for (int i = 0; i < 4; ++i)
        #pragma unroll
        for (int e = 0; e < 4; ++e) {
            const int row = wr * 64 + i * 16 + quad * 4 + e;
            const float inv = 1.0f / (redL[row][0] + redL[row][1] + redL[row][2] + redL[row][3]);
            const int g = b * 4096 + r0 + row;
            #pragma unroll
            for (int j = 0; j < 8; ++j)
                out[(size_t)g * 1024 + n0x + wc * 128 + j * 16 + m] = o[i][j][e] * inv;
        }
}

// ---------------------------------------------------------------------------
extern "C" void kernel_launch(void* const* d_in, const int* in_sizes, int n_in,
                              void* d_out, int out_size, void* d_ws, size_t ws_size,
                              hipStream_t stream)
{
    const float* x    = (const float*)d_in[0];
    const float* W    = (const float*)d_in[1];
    const float* bias = (const float*)d_in[2];
    float* out = (float*)d_out;

    const size_t SZQ  = (size_t)4 * 4096 * 1024 * 2;     // 32 MiB each
    const size_t SZWT = (size_t)3072 * 1024 * 2;         // 6 MiB
    const size_t SZXB = (size_t)4 * 4096 * 1024 * 2;     // 32 MiB (bf16 x)
    const size_t NEED  = 3 * SZQ + SZWT;
    const size_t NEED2 = NEED + SZXB;
    if (ws_size < NEED) return;

    ushort_t* q  = (ushort_t*)d_ws;
    ushort_t* k  = (ushort_t*)((char*)d_ws + SZQ);
    ushort_t* vt = (ushort_t*)((char*)d_ws + 2 * SZQ);
    ushort_t* Wt = (ushort_t*)((char*)d_ws + 3 * SZQ);
    ushort_t* xb = (ushort_t*)((char*)d_ws + NEED);

    wt_kernel <<<dim3(16, 48),   256, 0, stream>>>(W, Wt);
    if (ws_size >= NEED2) {
        xcvt      <<<dim3(8192),    256, 0, stream>>>(x, xb);
        qkv_mfma2 <<<dim3(24, 128), 256, 0, stream>>>(xb, Wt, bias, q, k, vt);
    } else {
        qkv_mfma  <<<dim3(24, 128), 256, 0, stream>>>(x, Wt, bias, q, k, vt);
    }
    fused_attn<<<dim3(2, 32, 4), 512, 0, stream>>>(q, k, vt, out);
}

// Round 4
// 744.739 us; speedup vs baseline: 1.1951x; 1.1951x over previous
//
#include <hip/hip_runtime.h>
#include <math.h>

typedef unsigned short ushort_t;
typedef __attribute__((ext_vector_type(8))) short short8;
typedef __attribute__((ext_vector_type(4))) float floatx4;

#define VMCNT(n) asm volatile("s_waitcnt vmcnt(" #n ")" ::: "memory")

// fp32 -> bf16 round-to-nearest-even, bit-level (no NaN inputs here)
__device__ inline ushort_t f2bf(float x) {
    union { float f; unsigned int u; } c; c.f = x;
    unsigned int r = (c.u + 0x7fffu + ((c.u >> 16) & 1u)) >> 16;
    return (ushort_t)r;
}

// async global->LDS, 16 B per lane; lds base must be wave-uniform
__device__ __forceinline__ void glds16(const ushort_t* g, ushort_t* l) {
    __builtin_amdgcn_global_load_lds(
        (const __attribute__((address_space(1))) unsigned int*)g,
        (__attribute__((address_space(3))) unsigned int*)l,
        16, 0, 0);
}

// bank-conflict swizzle: XOR 16B-slot bits (4:6) with bits (7:9).
// Involution; valid for 64B-row tiles (pair-of-rows key) and 128B-row tiles.
__device__ __forceinline__ unsigned swzo(unsigned off) {
    return off ^ ((off >> 3) & 0x70u);
}

// ---------------------------------------------------------------------------
// Kernel 0: W [1024,3072] fp32  ->  W_t [3072,1024] bf16  (unchanged, passing)
__global__ __launch_bounds__(256)
void wt_kernel(const float* __restrict__ W, ushort_t* __restrict__ Wt)
{
    __shared__ float tile[64][65];
    const int k0 = blockIdx.x * 64;
    const int n0 = blockIdx.y * 64;
    const int tid = threadIdx.x;
    #pragma unroll
    for (int ii = 0; ii < 16; ++ii) {
        int idx = ii * 256 + tid;
        int r = idx >> 6, c = idx & 63;
        tile[r][c] = W[(size_t)(k0 + r) * 3072 + n0 + c];
    }
    __syncthreads();
    #pragma unroll
    for (int ii = 0; ii < 16; ++ii) {
        int idx = ii * 256 + tid;
        int r = idx >> 6, c = idx & 63;
        Wt[(size_t)(n0 + r) * 1024 + k0 + c] = f2bf(tile[c][r]);
    }
}

// ---------------------------------------------------------------------------
// Kernel 0b: x [B,S,D] fp32 -> xb bf16 (prepass so qkv can glds16 both sides)
__global__ __launch_bounds__(256)
void xcvt(const float* __restrict__ x, ushort_t* __restrict__ xb)
{
    const int i = (blockIdx.x * 256 + threadIdx.x) * 8;   // exact: 16777216 elems
    float4 f0 = *(const float4*)(x + i);
    float4 f1 = *(const float4*)(x + i + 4);
    ushort_t tmp[8] __attribute__((aligned(16)));
    tmp[0]=f2bf(f0.x); tmp[1]=f2bf(f0.y); tmp[2]=f2bf(f0.z); tmp[3]=f2bf(f0.w);
    tmp[4]=f2bf(f1.x); tmp[5]=f2bf(f1.y); tmp[6]=f2bf(f1.z); tmp[7]=f2bf(f1.w);
    *(uint4*)(xb + i) = *(const uint4*)tmp;
}

// ---------------------------------------------------------------------------
// Kernel 1 (fallback, unchanged): qkv projection, reg-staged fp32 A
__global__ __launch_bounds__(256)
void qkv_mfma(const float* __restrict__ x, const ushort_t* __restrict__ Wt,
              const float* __restrict__ bias,
              ushort_t* __restrict__ q, ushort_t* __restrict__ k,
              ushort_t* __restrict__ vt)
{
    __shared__ ushort_t As[128][72];
    __shared__ ushort_t Bs[128][72];
    const int tid = threadIdx.x;
    const int w = tid >> 6, lane = tid & 63;
    const int m = lane & 15, quad = lane >> 4;
    const int col0 = blockIdx.x * 128;
    const int r0   = blockIdx.y * 128;

    floatx4 o[2][8];
    #pragma unroll
    for (int rf = 0; rf < 2; ++rf)
        #pragma unroll
        for (int nf = 0; nf < 8; ++nf)
            o[rf][nf] = (floatx4){0.f, 0.f, 0.f, 0.f};

    for (int kc = 0; kc < 16; ++kc) {
        const int kdim = kc * 64;
        __syncthreads();
        #pragma unroll
        for (int ii = 0; ii < 4; ++ii) {
            int lin = ii * 256 + tid;
            int row = lin >> 3, seg = lin & 7;
            const float* src = x + (size_t)(r0 + row) * 1024 + kdim + seg * 8;
            float4 f0 = *(const float4*)src;
            float4 f1 = *(const float4*)(src + 4);
            ushort_t tmp[8] __attribute__((aligned(16)));
            tmp[0]=f2bf(f0.x); tmp[1]=f2bf(f0.y); tmp[2]=f2bf(f0.z); tmp[3]=f2bf(f0.w);
            tmp[4]=f2bf(f1.x); tmp[5]=f2bf(f1.y); tmp[6]=f2bf(f1.z); tmp[7]=f2bf(f1.w);
            *(uint4*)&As[row][seg * 8] = *(const uint4*)tmp;
        }
        #pragma unroll
        for (int ii = 0; ii < 4; ++ii) {
            int lin = ii * 256 + tid;
            int row = lin >> 3, seg = lin & 7;
            const ushort_t* src = Wt + (size_t)(col0 + row) * 1024 + kdim + seg * 8;
            *(uint4*)&Bs[row][seg * 8] = *(const uint4*)src;
        }
        __syncthreads();
        #pragma unroll
        for (int kk = 0; kk < 2; ++kk) {
            short8 af[2];
            #pragma unroll
            for (int rf = 0; rf < 2; ++rf)
                af[rf] = *(const short8*)&As[w * 32 + rf * 16 + m][kk * 32 + quad * 8];
            #pragma unroll
            for (int nf = 0; nf < 8; ++nf) {
                short8 bf = *(const short8*)&Bs[nf * 16 + m][kk * 32 + quad * 8];
                #pragma unroll
                for (int rf = 0; rf < 2; ++rf)
                    o[rf][nf] = __builtin_amdgcn_mfma_f32_16x16x32_bf16(af[rf], bf, o[rf][nf], 0, 0, 0);
            }
        }
    }

    const int which = col0 >> 10;
    const int dbase = col0 & 1023;
    float bias_v[8];
    #pragma unroll
    for (int nf = 0; nf < 8; ++nf) bias_v[nf] = bias[col0 + nf * 16 + m];

    #pragma unroll
    for (int rf = 0; rf < 2; ++rf) {
        #pragma unroll
        for (int e = 0; e < 4; ++e) {
            const int g = r0 + w * 32 + rf * 16 + quad * 4 + e;
            #pragma unroll
            for (int nf = 0; nf < 8; ++nf) {
                const int c = dbase + nf * 16 + m;
                float val = o[rf][nf][e] + bias_v[nf];
                if (which == 0) {
                    q[(size_t)g * 1024 + c] = f2bf(val * 0.03125f);
                } else if (which == 1) {
                    k[(size_t)g * 1024 + c] = f2bf(val);
                } else {
                    vt[(size_t)(g >> 12) * 4194304 + (size_t)c * 4096 + (g & 4095)] = f2bf(val);
                }
            }
        }
    }
}

// ---------------------------------------------------------------------------
// Kernel 1 v3 (KEPT from round 3, measured -46us): qkv projection, m97-style;
// V-third epilogue stages the output tile in LDS (two 64-col passes) and
// stores vt with coalesced 16B column runs instead of 2B stride-8KB scatters.
__global__ __launch_bounds__(256)
void qkv_mfma2(const ushort_t* __restrict__ xb, const ushort_t* __restrict__ Wt,
               const float* __restrict__ bias,
               ushort_t* __restrict__ q, ushort_t* __restrict__ k,
               ushort_t* __restrict__ vt)
{
    __shared__ __align__(1024) ushort_t smem[2 * 128 * 64];
    ushort_t (*As)[64] = (ushort_t (*)[64])smem;
    ushort_t (*Bs)[64] = (ushort_t (*)[64])(smem + 128 * 64);
    const int tid = threadIdx.x;
    const int w = tid >> 6, lane = tid & 63;
    const int m = lane & 15, quad = lane >> 4;
    const int lx = lane ^ ((lane >> 3) & 7);
    const int sr = lx >> 3, sc = (lx & 7) * 8;
    const int col0 = blockIdx.x * 128;
    const int r0   = blockIdx.y * 128;

    floatx4 o[2][8];
    #pragma unroll
    for (int rf = 0; rf < 2; ++rf)
        #pragma unroll
        for (int nf = 0; nf < 8; ++nf)
            o[rf][nf] = (floatx4){0.f, 0.f, 0.f, 0.f};

    for (int kc = 0; kc < 16; ++kc) {
        const int kdim = kc * 64;
        __syncthreads();
        #pragma unroll
        for (int ii = 0; ii < 4; ++ii) {
            glds16(xb + (size_t)(r0 + w * 32 + ii * 8 + sr) * 1024 + kdim + sc,
                   &As[w * 32 + ii * 8][0]);
            glds16(Wt + (size_t)(col0 + w * 32 + ii * 8 + sr) * 1024 + kdim + sc,
                   &Bs[w * 32 + ii * 8][0]);
        }
        __syncthreads();
        #pragma unroll
        for (int kk = 0; kk < 2; ++kk) {
            short8 af[2];
            #pragma unroll
            for (int rf = 0; rf < 2; ++rf)
                af[rf] = *(const short8*)((const char*)As +
                          swzo((unsigned)((w * 32 + rf * 16 + m) * 128 + kk * 64 + quad * 16)));
            #pragma unroll
            for (int nf = 0; nf < 8; ++nf) {
                short8 bf = *(const short8*)((const char*)Bs +
                          swzo((unsigned)((nf * 16 + m) * 128 + kk * 64 + quad * 16)));
                #pragma unroll
                for (int rf = 0; rf < 2; ++rf)
                    o[rf][nf] = __builtin_amdgcn_mfma_f32_16x16x32_bf16(af[rf], bf, o[rf][nf], 0, 0, 0);
            }
        }
    }

    const int which = col0 >> 10;
    const int dbase = col0 & 1023;
    float bias_v[8];
    #pragma unroll
    for (int nf = 0; nf < 8; ++nf) bias_v[nf] = bias[col0 + nf * 16 + m];

    if (which == 2) {
        // transpose-store vt: stage [64 cols][128 rows] in LDS, store 16B runs
        const size_t voffb = (size_t)(r0 >> 12) * 4194304;
        const int grow0 = r0 & 4095;
        ushort_t (*T)[136] = (ushort_t (*)[136])smem;
        #pragma unroll
        for (int p = 0; p < 2; ++p) {
            __syncthreads();   // T region free (MFMA reads / prev-pass stores done)
            #pragma unroll
            for (int rf = 0; rf < 2; ++rf)
                #pragma unroll
                for (int e = 0; e < 4; ++e) {
                    const int row = w * 32 + rf * 16 + quad * 4 + e;
                    #pragma unroll
                    for (int nn = 0; nn < 4; ++nn) {
                        const int nf = p * 4 + nn;
                        T[nn * 16 + m][row] = f2bf(o[rf][nf][e] + bias_v[nf]);
                    }
                }
            __syncthreads();
            #pragma unroll
            for (int ii = 0; ii < 4; ++ii) {
                int idx = ii * 256 + tid;
                int c = idx >> 4, seg = idx & 15;
                *(uint4*)&vt[voffb + (size_t)(dbase + p * 64 + c) * 4096 + grow0 + seg * 8]
                    = *(const uint4*)&T[c][seg * 8];
            }
        }
    } else {
        #pragma unroll
        for (int rf = 0; rf < 2; ++rf) {
            #pragma unroll
            for (int e = 0; e < 4; ++e) {
                const int g = r0 + w * 32 + rf * 16 + quad * 4 + e;
                #pragma unroll
                for (int nf = 0; nf < 8; ++nf) {
                    const int c = dbase + nf * 16 + m;
                    float val = o[rf][nf][e] + bias_v[nf];
                    if (which == 0) {
                        q[(size_t)g * 1024 + c] = f2bf(val * 0.03125f);
                    } else {
                        k[(size_t)g * 1024 + c] = f2bf(val);
                    }
                }
            }
        }
    }
}

// ---------------------------------------------------------------------------
// Kernel 2 v8: REVERT to the round-2 v6 structure (495us measured; round-3's
// deeper pipeline collapsed L2 locality: FETCH +43%, WRITE x2, Mfma 37->26).
// Single added change vs v6: V(0) staging hoisted BEFORE the exp phase, so
// its HBM/L2 latency hides under ~600 cyc of VALU instead of being drained
// cold at the following __syncthreads. No barrier/vmcnt semantics change.
__global__ __launch_bounds__(512, 2)
void fused_attn(const ushort_t* __restrict__ q, const ushort_t* __restrict__ kb_,
                const ushort_t* __restrict__ vt, float* __restrict__ out)
{
    // LDS map (141312 B total):
    //   [0,24576)        Qs[3][128][32]   -- aliased by Pls
    //   [24576,73728)    Ks[3][256][32]   -- aliased by Pls
    //   [0,67584)        Pls[128][264]    (stride 132 words == 4 mod 32: balanced)
    //   [73728,139264)   Vs[2][512][32]
    //   [139264,141312)  redL[128][4]
    __shared__ __align__(1024) unsigned char lds[141312];
    ushort_t (*Qs)[128][32] = (ushort_t(*)[128][32])(lds);
    ushort_t (*Ks)[256][32] = (ushort_t(*)[256][32])(lds + 24576);
    ushort_t (*Pls)[264]    = (ushort_t(*)[264])(lds);
    ushort_t (*Vs)[512][32] = (ushort_t(*)[512][32])(lds + 73728);
    float    (*redL)[4]     = (float(*)[4])(lds + 139264);

    const int tid  = threadIdx.x;
    const int w    = tid >> 6, lane = tid & 63;
    const int m    = lane & 15, quad = lane >> 4;
    const int wr   = w & 1, wc = w >> 1;
    // swizzled staging source lane: 1024B region = 16 rows x 64 B
    const int lx   = lane ^ ((lane >> 3) & 7);
    const int lr   = lx >> 2, lc = (lx & 3) * 8;
    const int n0x  = blockIdx.x * 512;
    const int r0   = blockIdx.y * 128;
    const int b    = blockIdx.z;
    const size_t qoff = (size_t)b * 4096 * 1024;
    const size_t voff = (size_t)b * 4194304;

    // hoisted swizzled read offsets (bytes, within a tile)
    unsigned qof[4], kof[4], vof[8];
    #pragma unroll
    for (int i = 0; i < 4; ++i)
        qof[i] = swzo((unsigned)((wr * 64 + i * 16 + m) * 64 + quad * 16));
    #pragma unroll
    for (int j = 0; j < 4; ++j)
        kof[j] = swzo((unsigned)((wc * 64 + j * 16 + m) * 64 + quad * 16));
    #pragma unroll
    for (int j = 0; j < 8; ++j)
        vof[j] = swzo((unsigned)((wc * 128 + j * 16 + m) * 64 + quad * 16));

    // hoisted glds source row bases
    const ushort_t* qsrc  = q   + qoff + (size_t)(r0 + w * 16 + lr) * 1024 + lc;
    const ushort_t* ksrc0 = kb_ + qoff + (size_t)(w * 32 + lr) * 1024 + lc;
    const ushort_t* ksrc1 = kb_ + qoff + (size_t)(w * 32 + 16 + lr) * 1024 + lc;

    floatx4 o[4][8];
    #pragma unroll
    for (int i = 0; i < 4; ++i)
        #pragma unroll
        for (int j = 0; j < 8; ++j)
            o[i][j] = (floatx4){0.f, 0.f, 0.f, 0.f};
    float lsum[4][4] = {};

    for (int kt = 0; kt < 16; ++kt) {
        const int kbase = kt * 256;

        floatx4 s[4][4];
        #pragma unroll
        for (int i = 0; i < 4; ++i)
            #pragma unroll
            for (int j = 0; j < 4; ++j)
                s[i][j] = (floatx4){0.f, 0.f, 0.f, 0.f};

        // ---- S = Q K^T over 1024 dims, kc = 32-dim chunks, triple-buffered ----
        // prologue: stage kc=0 into buf 0. Safe: previous kt ended on a full
        // __syncthreads (or kernel entry), so Pls/Qs region is free.
        glds16(qsrc,                        &Qs[0][w * 16][0]);
        glds16(ksrc0 + (size_t)kbase * 1024, &Ks[0][w * 32][0]);
        glds16(ksrc1 + (size_t)kbase * 1024, &Ks[0][w * 32 + 16][0]);
        {
            int cur = 0;
            for (int kc = 0; kc < 32; ++kc) {
                if (kc < 31) {
                    const int nxt = (cur == 2) ? 0 : cur + 1;
                    const int kd = (kc + 1) * 32;
                    glds16(qsrc + kd,                             &Qs[nxt][w * 16][0]);
                    glds16(ksrc0 + (size_t)kbase * 1024 + kd,     &Ks[nxt][w * 32][0]);
                    glds16(ksrc1 + (size_t)kbase * 1024 + kd,     &Ks[nxt][w * 32 + 16][0]);
                    VMCNT(3);   // this kc's 3 loads (issued last iter) done; 3 in flight
                } else {
                    VMCNT(0);   // final step: drain its own 3
                }
                __builtin_amdgcn_s_barrier();
                __builtin_amdgcn_sched_barrier(0);
                short8 af[4], bf[4];
                #pragma unroll
                for (int i = 0; i < 4; ++i)
                    af[i] = *(const short8*)((const char*)Qs[cur] + qof[i]);
                #pragma unroll
                for (int j = 0; j < 4; ++j)
                    bf[j] = *(const short8*)((const char*)Ks[cur] + kof[j]);
                __builtin_amdgcn_s_setprio(1);
                #pragma unroll
                for (int i = 0; i < 4; ++i)
                    #pragma unroll
                    for (int j = 0; j < 4; ++j)
                        s[i][j] = __builtin_amdgcn_mfma_f32_16x16x32_bf16(af[i], bf[j], s[i][j], 0, 0, 0);
                __builtin_amdgcn_s_setprio(0);
                cur = (cur == 2) ? 0 : cur + 1;
            }
        }
        __syncthreads();   // all waves done reading Qs/Ks (vmem empty: kc=31 drained)

        // ---- V(0) staging hoisted above exp: latency hides under the VALU phase.
        // Vs is free here: all Vs readers passed the previous kt's final barrier.
        #pragma unroll
        for (int i = 0; i < 4; ++i)
            glds16(vt + voff + (size_t)(n0x + w * 64 + i * 16 + lr) * 4096 + kbase + lc,
                   &Vs[0][w * 64 + i * 16][0]);

        // ---- exp -> Pls (aliases Qs/Ks: safe, all waves passed the barrier) ----
        #pragma unroll
        for (int i = 0; i < 4; ++i)
            #pragma unroll
            for (int j = 0; j < 4; ++j)
                #pragma unroll
                for (int e = 0; e < 4; ++e) {
                    float pv = __expf(s[i][j][e]);
                    lsum[i][e] += pv;
                    Pls[wr * 64 + i * 16 + quad * 4 + e][wc * 64 + j * 16 + m] = f2bf(pv);
                }
        __syncthreads();   // Pls visible to all waves; V(0) drained here (window = exp)

        // ---- O += P V, vc = 32-key chunks, Vs double-buffered (drain style) ----
        for (int vc = 0; vc < 8; ++vc) {
            const int p = vc & 1;
            if (vc < 7) {
                const int kd = kbase + (vc + 1) * 32;
                #pragma unroll
                for (int i = 0; i < 4; ++i)
                    glds16(vt + voff + (size_t)(n0x + w * 64 + i * 16 + lr) * 4096 + kd + lc,
                           &Vs[p ^ 1][w * 64 + i * 16][0]);
            }
            short8 ap[4], bv[8];
            #pragma unroll
            for (int i = 0; i < 4; ++i)
                ap[i] = *(const short8*)&Pls[wr * 64 + i * 16 + m][vc * 32 + quad * 8];
            #pragma unroll
            for (int j = 0; j < 8; ++j)
                bv[j] = *(const short8*)((const char*)Vs[p] + vof[j]);
            __builtin_amdgcn_s_setprio(1);
            #pragma unroll
            for (int i = 0; i < 4; ++i)
                #pragma unroll
                for (int j = 0; j < 8; ++j)
                    o[i][j] = __builtin_amdgcn_mfma_f32_16x16x32_bf16(ap[i], bv[j], o[i][j], 0, 0, 0);
            __builtin_amdgcn_s_setprio(0);
            __syncthreads();   // Vs buf p free for vc+2; after vc=7: Pls/Qs free for next kt
        }
    }

    // ---- finalize: reduce lsum over the 16 m-lanes, combine col-quarters ----
    #pragma unroll
    for (int i = 0; i < 4; ++i)
        #pragma unroll
        for (int e = 0; e < 4; ++e) {
            float l = lsum[i][e];
            l += __shfl_xor(l, 1);
            l += __shfl_xor(l, 2);
            l += __shfl_xor(l, 4);
            l += __shfl_xor(l, 8);
            if (m == 0) redL[wr * 64 + i * 16 + quad * 4 + e][wc] = l;
        }
    __syncthreads();
    #pragma unroll
    for (int i = 0; i < 4; ++i)
        #pragma unroll
        for (int e = 0; e < 4; ++e) {
            const int row = wr * 64 + i * 16 + quad * 4 + e;
            const float inv = 1.0f / (redL[row][0] + redL[row][1] + redL[row][2] + redL[row][3]);
            const int g = b * 4096 + r0 + row;
            #pragma unroll
            for (int j = 0; j < 8; ++j)
                out[(size_t)g * 1024 + n0x + wc * 128 + j * 16 + m] = o[i][j][e] * inv;
        }
}

// ---------------------------------------------------------------------------
extern "C" void kernel_launch(void* const* d_in, const int* in_sizes, int n_in,
                              void* d_out, int out_size, void* d_ws, size_t ws_size,
                              hipStream_t stream)
{
    const float* x    = (const float*)d_in[0];
    const float* W    = (const float*)d_in[1];
    const float* bias = (const float*)d_in[2];
    float* out = (float*)d_out;

    const size_t SZQ  = (size_t)4 * 4096 * 1024 * 2;     // 32 MiB each
    const size_t SZWT = (size_t)3072 * 1024 * 2;         // 6 MiB
    const size_t SZXB = (size_t)4 * 4096 * 1024 * 2;     // 32 MiB (bf16 x)
    const size_t NEED  = 3 * SZQ + SZWT;
    const size_t NEED2 = NEED + SZXB;
    if (ws_size < NEED) return;

    ushort_t* q  = (ushort_t*)d_ws;
    ushort_t* k  = (ushort_t*)((char*)d_ws + SZQ);
    ushort_t* vt = (ushort_t*)((char*)d_ws + 2 * SZQ);
    ushort_t* Wt = (ushort_t*)((char*)d_ws + 3 * SZQ);
    ushort_t* xb = (ushort_t*)((char*)d_ws + NEED);

    wt_kernel <<<dim3(16, 48),   256, 0, stream>>>(W, Wt);
    if (ws_size >= NEED2) {
        xcvt      <<<dim3(8192),    256, 0, stream>>>(x, xb);
        qkv_mfma2 <<<dim3(24, 128), 256, 0, stream>>>(xb, Wt, bias, q, k, vt);
    } else {
        qkv_mfma  <<<dim3(24, 128), 256, 0, stream>>>(x, Wt, bias, q, k, vt);
    }
    fused_attn<<<dim3(2, 32, 4), 512, 0, stream>>>(q, k, vt, out);
}

// Round 5
// 688.010 us; speedup vs baseline: 1.2937x; 1.0825x over previous
//
#include <hip/hip_runtime.h>
#include <math.h>

typedef unsigned short ushort_t;
typedef __attribute__((ext_vector_type(8))) short short8;
typedef __attribute__((ext_vector_type(4))) float floatx4;

#define VMCNT(n) asm volatile("s_waitcnt vmcnt(" #n ")" ::: "memory")

// fp32 -> bf16 round-to-nearest-even, bit-level (no NaN inputs here)
__device__ inline ushort_t f2bf(float x) {
    union { float f; unsigned int u; } c; c.f = x;
    unsigned int r = (c.u + 0x7fffu + ((c.u >> 16) & 1u)) >> 16;
    return (ushort_t)r;
}

// async global->LDS, 16 B per lane; lds base must be wave-uniform
__device__ __forceinline__ void glds16(const ushort_t* g, ushort_t* l) {
    __builtin_amdgcn_global_load_lds(
        (const __attribute__((address_space(1))) unsigned int*)g,
        (__attribute__((address_space(3))) unsigned int*)l,
        16, 0, 0);
}

// bank-conflict swizzle: XOR 16B-slot bits (4:6) with bits (7:9).
// Involution; valid for 64B-row tiles (pair-of-rows key) and 128B-row tiles.
__device__ __forceinline__ unsigned swzo(unsigned off) {
    return off ^ ((off >> 3) & 0x70u);
}

// ---------------------------------------------------------------------------
// Kernel 0: W [1024,3072] fp32  ->  W_t [3072,1024] bf16  (unchanged, passing)
__global__ __launch_bounds__(256)
void wt_kernel(const float* __restrict__ W, ushort_t* __restrict__ Wt)
{
    __shared__ float tile[64][65];
    const int k0 = blockIdx.x * 64;
    const int n0 = blockIdx.y * 64;
    const int tid = threadIdx.x;
    #pragma unroll
    for (int ii = 0; ii < 16; ++ii) {
        int idx = ii * 256 + tid;
        int r = idx >> 6, c = idx & 63;
        tile[r][c] = W[(size_t)(k0 + r) * 3072 + n0 + c];
    }
    __syncthreads();
    #pragma unroll
    for (int ii = 0; ii < 16; ++ii) {
        int idx = ii * 256 + tid;
        int r = idx >> 6, c = idx & 63;
        Wt[(size_t)(n0 + r) * 1024 + k0 + c] = f2bf(tile[c][r]);
    }
}

// ---------------------------------------------------------------------------
// Kernel 0b: x [B,S,D] fp32 -> xb bf16 (prepass so qkv can glds16 both sides)
__global__ __launch_bounds__(256)
void xcvt(const float* __restrict__ x, ushort_t* __restrict__ xb)
{
    const int i = (blockIdx.x * 256 + threadIdx.x) * 8;   // exact: 16777216 elems
    float4 f0 = *(const float4*)(x + i);
    float4 f1 = *(const float4*)(x + i + 4);
    ushort_t tmp[8] __attribute__((aligned(16)));
    tmp[0]=f2bf(f0.x); tmp[1]=f2bf(f0.y); tmp[2]=f2bf(f0.z); tmp[3]=f2bf(f0.w);
    tmp[4]=f2bf(f1.x); tmp[5]=f2bf(f1.y); tmp[6]=f2bf(f1.z); tmp[7]=f2bf(f1.w);
    *(uint4*)(xb + i) = *(const uint4*)tmp;
}

// ---------------------------------------------------------------------------
// Kernel 1 (fallback, unchanged): qkv projection, reg-staged fp32 A
__global__ __launch_bounds__(256)
void qkv_mfma(const float* __restrict__ x, const ushort_t* __restrict__ Wt,
              const float* __restrict__ bias,
              ushort_t* __restrict__ q, ushort_t* __restrict__ k,
              ushort_t* __restrict__ vt)
{
    __shared__ ushort_t As[128][72];
    __shared__ ushort_t Bs[128][72];
    const int tid = threadIdx.x;
    const int w = tid >> 6, lane = tid & 63;
    const int m = lane & 15, quad = lane >> 4;
    const int col0 = blockIdx.x * 128;
    const int r0   = blockIdx.y * 128;

    floatx4 o[2][8];
    #pragma unroll
    for (int rf = 0; rf < 2; ++rf)
        #pragma unroll
        for (int nf = 0; nf < 8; ++nf)
            o[rf][nf] = (floatx4){0.f, 0.f, 0.f, 0.f};

    for (int kc = 0; kc < 16; ++kc) {
        const int kdim = kc * 64;
        __syncthreads();
        #pragma unroll
        for (int ii = 0; ii < 4; ++ii) {
            int lin = ii * 256 + tid;
            int row = lin >> 3, seg = lin & 7;
            const float* src = x + (size_t)(r0 + row) * 1024 + kdim + seg * 8;
            float4 f0 = *(const float4*)src;
            float4 f1 = *(const float4*)(src + 4);
            ushort_t tmp[8] __attribute__((aligned(16)));
            tmp[0]=f2bf(f0.x); tmp[1]=f2bf(f0.y); tmp[2]=f2bf(f0.z); tmp[3]=f2bf(f0.w);
            tmp[4]=f2bf(f1.x); tmp[5]=f2bf(f1.y); tmp[6]=f2bf(f1.z); tmp[7]=f2bf(f1.w);
            *(uint4*)&As[row][seg * 8] = *(const uint4*)tmp;
        }
        #pragma unroll
        for (int ii = 0; ii < 4; ++ii) {
            int lin = ii * 256 + tid;
            int row = lin >> 3, seg = lin & 7;
            const ushort_t* src = Wt + (size_t)(col0 + row) * 1024 + kdim + seg * 8;
            *(uint4*)&Bs[row][seg * 8] = *(const uint4*)src;
        }
        __syncthreads();
        #pragma unroll
        for (int kk = 0; kk < 2; ++kk) {
            short8 af[2];
            #pragma unroll
            for (int rf = 0; rf < 2; ++rf)
                af[rf] = *(const short8*)&As[w * 32 + rf * 16 + m][kk * 32 + quad * 8];
            #pragma unroll
            for (int nf = 0; nf < 8; ++nf) {
                short8 bf = *(const short8*)&Bs[nf * 16 + m][kk * 32 + quad * 8];
                #pragma unroll
                for (int rf = 0; rf < 2; ++rf)
                    o[rf][nf] = __builtin_amdgcn_mfma_f32_16x16x32_bf16(af[rf], bf, o[rf][nf], 0, 0, 0);
            }
        }
    }

    const int which = col0 >> 10;
    const int dbase = col0 & 1023;
    float bias_v[8];
    #pragma unroll
    for (int nf = 0; nf < 8; ++nf) bias_v[nf] = bias[col0 + nf * 16 + m];

    #pragma unroll
    for (int rf = 0; rf < 2; ++rf) {
        #pragma unroll
        for (int e = 0; e < 4; ++e) {
            const int g = r0 + w * 32 + rf * 16 + quad * 4 + e;
            #pragma unroll
            for (int nf = 0; nf < 8; ++nf) {
                const int c = dbase + nf * 16 + m;
                float val = o[rf][nf][e] + bias_v[nf];
                if (which == 0) {
                    q[(size_t)g * 1024 + c] = f2bf(val * 0.03125f);
                } else if (which == 1) {
                    k[(size_t)g * 1024 + c] = f2bf(val);
                } else {
                    vt[(size_t)(g >> 12) * 4194304 + (size_t)c * 4096 + (g & 4095)] = f2bf(val);
                }
            }
        }
    }
}

// ---------------------------------------------------------------------------
// Kernel 1 v3 (kept, measured -27us): qkv projection, m97-style; V-third
// epilogue stages the output tile in LDS and stores vt as coalesced 16B runs.
__global__ __launch_bounds__(256)
void qkv_mfma2(const ushort_t* __restrict__ xb, const ushort_t* __restrict__ Wt,
               const float* __restrict__ bias,
               ushort_t* __restrict__ q, ushort_t* __restrict__ k,
               ushort_t* __restrict__ vt)
{
    __shared__ __align__(1024) ushort_t smem[2 * 128 * 64];
    ushort_t (*As)[64] = (ushort_t (*)[64])smem;
    ushort_t (*Bs)[64] = (ushort_t (*)[64])(smem + 128 * 64);
    const int tid = threadIdx.x;
    const int w = tid >> 6, lane = tid & 63;
    const int m = lane & 15, quad = lane >> 4;
    const int lx = lane ^ ((lane >> 3) & 7);
    const int sr = lx >> 3, sc = (lx & 7) * 8;
    const int col0 = blockIdx.x * 128;
    const int r0   = blockIdx.y * 128;

    floatx4 o[2][8];
    #pragma unroll
    for (int rf = 0; rf < 2; ++rf)
        #pragma unroll
        for (int nf = 0; nf < 8; ++nf)
            o[rf][nf] = (floatx4){0.f, 0.f, 0.f, 0.f};

    for (int kc = 0; kc < 16; ++kc) {
        const int kdim = kc * 64;
        __syncthreads();
        #pragma unroll
        for (int ii = 0; ii < 4; ++ii) {
            glds16(xb + (size_t)(r0 + w * 32 + ii * 8 + sr) * 1024 + kdim + sc,
                   &As[w * 32 + ii * 8][0]);
            glds16(Wt + (size_t)(col0 + w * 32 + ii * 8 + sr) * 1024 + kdim + sc,
                   &Bs[w * 32 + ii * 8][0]);
        }
        __syncthreads();
        #pragma unroll
        for (int kk = 0; kk < 2; ++kk) {
            short8 af[2];
            #pragma unroll
            for (int rf = 0; rf < 2; ++rf)
                af[rf] = *(const short8*)((const char*)As +
                          swzo((unsigned)((w * 32 + rf * 16 + m) * 128 + kk * 64 + quad * 16)));
            #pragma unroll
            for (int nf = 0; nf < 8; ++nf) {
                short8 bf = *(const short8*)((const char*)Bs +
                          swzo((unsigned)((nf * 16 + m) * 128 + kk * 64 + quad * 16)));
                #pragma unroll
                for (int rf = 0; rf < 2; ++rf)
                    o[rf][nf] = __builtin_amdgcn_mfma_f32_16x16x32_bf16(af[rf], bf, o[rf][nf], 0, 0, 0);
            }
        }
    }

    const int which = col0 >> 10;
    const int dbase = col0 & 1023;
    float bias_v[8];
    #pragma unroll
    for (int nf = 0; nf < 8; ++nf) bias_v[nf] = bias[col0 + nf * 16 + m];

    if (which == 2) {
        // transpose-store vt: stage [64 cols][128 rows] in LDS, store 16B runs
        const size_t voffb = (size_t)(r0 >> 12) * 4194304;
        const int grow0 = r0 & 4095;
        ushort_t (*T)[136] = (ushort_t (*)[136])smem;
        #pragma unroll
        for (int p = 0; p < 2; ++p) {
            __syncthreads();   // T region free (MFMA reads / prev-pass stores done)
            #pragma unroll
            for (int rf = 0; rf < 2; ++rf)
                #pragma unroll
                for (int e = 0; e < 4; ++e) {
                    const int row = w * 32 + rf * 16 + quad * 4 + e;
                    #pragma unroll
                    for (int nn = 0; nn < 4; ++nn) {
                        const int nf = p * 4 + nn;
                        T[nn * 16 + m][row] = f2bf(o[rf][nf][e] + bias_v[nf]);
                    }
                }
            __syncthreads();
            #pragma unroll
            for (int ii = 0; ii < 4; ++ii) {
                int idx = ii * 256 + tid;
                int c = idx >> 4, seg = idx & 15;
                *(uint4*)&vt[voffb + (size_t)(dbase + p * 64 + c) * 4096 + grow0 + seg * 8]
                    = *(const uint4*)&T[c][seg * 8];
            }
        }
    } else {
        #pragma unroll
        for (int rf = 0; rf < 2; ++rf) {
            #pragma unroll
            for (int e = 0; e < 4; ++e) {
                const int g = r0 + w * 32 + rf * 16 + quad * 4 + e;
                #pragma unroll
                for (int nf = 0; nf < 8; ++nf) {
                    const int c = dbase + nf * 16 + m;
                    float val = o[rf][nf][e] + bias_v[nf];
                    if (which == 0) {
                        q[(size_t)g * 1024 + c] = f2bf(val * 0.03125f);
                    } else {
                        k[(size_t)g * 1024 + c] = f2bf(val);
                    }
                }
            }
        }
    }
}

// ---------------------------------------------------------------------------
// Kernel 2 v9: v6 structure (V-hoist reverted; 495us known) + two additions:
//  (a) swapped QK^T operands: s[j][i] = mfma(bf[j], af[i]) computes S^T
//      fragments, so each lane holds 4 CONSECUTIVE key-cols of one q-row
//      (row = i*16+m, cols = j*16+quad*4+e). exp->Pls becomes 16 ds_write_b64
//      per wave (was 64 ds_write_b16); lsum shrinks to [4]; finalize reduce
//      is 2 shuffles (quad axis) instead of 4 (m axis). P content unchanged.
//  (b) XCD-aware block swizzle: 1-D grid 256; bid -> (batch, colhalf, rowtile)
//      such that batch z occupies dispatch slots == {2z, 2z+1} (mod 8), i.e.
//      2 XCDs per batch -> K/V tile working set ~1MB per XCD L2 (was 4 batches
//      x 1MB thrashing 4MB L2). Bijective: bid = (n>>1)*8 + 2z + (n&1).
__global__ __launch_bounds__(512, 2)
void fused_attn(const ushort_t* __restrict__ q, const ushort_t* __restrict__ kb_,
                const ushort_t* __restrict__ vt, float* __restrict__ out)
{
    // LDS map (141312 B total):
    //   [0,24576)        Qs[3][128][32]   -- aliased by Pls
    //   [24576,73728)    Ks[3][256][32]   -- aliased by Pls
    //   [0,67584)        Pls[128][264]    (stride 132 words == 4 mod 32: balanced)
    //   [73728,139264)   Vs[2][512][32]
    //   [139264,141312)  redL[128][4]
    __shared__ __align__(1024) unsigned char lds[141312];
    ushort_t (*Qs)[128][32] = (ushort_t(*)[128][32])(lds);
    ushort_t (*Ks)[256][32] = (ushort_t(*)[256][32])(lds + 24576);
    ushort_t (*Pls)[264]    = (ushort_t(*)[264])(lds);
    ushort_t (*Vs)[512][32] = (ushort_t(*)[512][32])(lds + 73728);
    float    (*redL)[4]     = (float(*)[4])(lds + 139264);

    const int tid  = threadIdx.x;
    const int w    = tid >> 6, lane = tid & 63;
    const int m    = lane & 15, quad = lane >> 4;
    const int wr   = w & 1, wc = w >> 1;
    // swizzled staging source lane: 1024B region = 16 rows x 64 B
    const int lx   = lane ^ ((lane >> 3) & 7);
    const int lr   = lx >> 2, lc = (lx & 3) * 8;
    // XCD-aware decode of the 1-D grid (bijective with bid=(n>>1)*8+2b+(n&1))
    const int bid  = blockIdx.x;
    const int b    = (bid & 7) >> 1;
    const int n    = ((bid >> 3) << 1) | (bid & 1);
    const int n0x  = (n >> 5) * 512;
    const int r0   = (n & 31) * 128;
    const size_t qoff = (size_t)b * 4096 * 1024;
    const size_t voff = (size_t)b * 4194304;

    // hoisted swizzled read offsets (bytes, within a tile)
    unsigned qof[4], kof[4], vof[8];
    #pragma unroll
    for (int i = 0; i < 4; ++i)
        qof[i] = swzo((unsigned)((wr * 64 + i * 16 + m) * 64 + quad * 16));
    #pragma unroll
    for (int j = 0; j < 4; ++j)
        kof[j] = swzo((unsigned)((wc * 64 + j * 16 + m) * 64 + quad * 16));
    #pragma unroll
    for (int j = 0; j < 8; ++j)
        vof[j] = swzo((unsigned)((wc * 128 + j * 16 + m) * 64 + quad * 16));

    // hoisted glds source row bases
    const ushort_t* qsrc  = q   + qoff + (size_t)(r0 + w * 16 + lr) * 1024 + lc;
    const ushort_t* ksrc0 = kb_ + qoff + (size_t)(w * 32 + lr) * 1024 + lc;
    const ushort_t* ksrc1 = kb_ + qoff + (size_t)(w * 32 + 16 + lr) * 1024 + lc;

    floatx4 o[4][8];
    #pragma unroll
    for (int i = 0; i < 4; ++i)
        #pragma unroll
        for (int j = 0; j < 8; ++j)
            o[i][j] = (floatx4){0.f, 0.f, 0.f, 0.f};
    float lsum[4] = {};

    for (int kt = 0; kt < 16; ++kt) {
        const int kbase = kt * 256;

        floatx4 s[4][4];   // s[j][i]: S^T fragment, K-block j x Q-block i
        #pragma unroll
        for (int j = 0; j < 4; ++j)
            #pragma unroll
            for (int i = 0; i < 4; ++i)
                s[j][i] = (floatx4){0.f, 0.f, 0.f, 0.f};

        // ---- S = Q K^T over 1024 dims, kc = 32-dim chunks, triple-buffered ----
        glds16(qsrc,                        &Qs[0][w * 16][0]);
        glds16(ksrc0 + (size_t)kbase * 1024, &Ks[0][w * 32][0]);
        glds16(ksrc1 + (size_t)kbase * 1024, &Ks[0][w * 32 + 16][0]);
        {
            int cur = 0;
            for (int kc = 0; kc < 32; ++kc) {
                if (kc < 31) {
                    const int nxt = (cur == 2) ? 0 : cur + 1;
                    const int kd = (kc + 1) * 32;
                    glds16(qsrc + kd,                             &Qs[nxt][w * 16][0]);
                    glds16(ksrc0 + (size_t)kbase * 1024 + kd,     &Ks[nxt][w * 32][0]);
                    glds16(ksrc1 + (size_t)kbase * 1024 + kd,     &Ks[nxt][w * 32 + 16][0]);
                    VMCNT(3);   // this kc's 3 loads (issued last iter) done; 3 in flight
                } else {
                    VMCNT(0);   // final step: drain its own 3
                }
                __builtin_amdgcn_s_barrier();
                __builtin_amdgcn_sched_barrier(0);
                short8 af[4], bf[4];
                #pragma unroll
                for (int i = 0; i < 4; ++i)
                    af[i] = *(const short8*)((const char*)Qs[cur] + qof[i]);
                #pragma unroll
                for (int j = 0; j < 4; ++j)
                    bf[j] = *(const short8*)((const char*)Ks[cur] + kof[j]);
                __builtin_amdgcn_s_setprio(1);
                #pragma unroll
                for (int j = 0; j < 4; ++j)
                    #pragma unroll
                    for (int i = 0; i < 4; ++i)
                        s[j][i] = __builtin_amdgcn_mfma_f32_16x16x32_bf16(bf[j], af[i], s[j][i], 0, 0, 0);
                __builtin_amdgcn_s_setprio(0);
                cur = (cur == 2) ? 0 : cur + 1;
            }
        }
        __syncthreads();   // all waves done reading Qs/Ks (vmem empty: kc=31 drained)

        // ---- exp -> Pls, packed b64 writes (4 consecutive key-cols per lane) ----
        #pragma unroll
        for (int i = 0; i < 4; ++i)
            #pragma unroll
            for (int j = 0; j < 4; ++j) {
                float p0 = __expf(s[j][i][0]);
                float p1 = __expf(s[j][i][1]);
                float p2 = __expf(s[j][i][2]);
                float p3 = __expf(s[j][i][3]);
                lsum[i] += (p0 + p1) + (p2 + p3);
                unsigned lo = (unsigned)f2bf(p0) | ((unsigned)f2bf(p1) << 16);
                unsigned hi = (unsigned)f2bf(p2) | ((unsigned)f2bf(p3) << 16);
                *(uint2*)&Pls[wr * 64 + i * 16 + m][wc * 64 + j * 16 + quad * 4] =
                    (uint2){lo, hi};
            }

        // ---- V(0) staging (v6 position: after exp, before the barrier) ----
        {
            #pragma unroll
            for (int i = 0; i < 4; ++i)
                glds16(vt + voff + (size_t)(n0x + w * 64 + i * 16 + lr) * 4096 + kbase + lc,
                       &Vs[0][w * 64 + i * 16][0]);
        }
        __syncthreads();   // Pls visible to all waves + V chunk 0 ready

        // ---- O += P V, vc = 32-key chunks, Vs double-buffered (drain style) ----
        for (int vc = 0; vc < 8; ++vc) {
            const int p = vc & 1;
            if (vc < 7) {
                const int kd = kbase + (vc + 1) * 32;
                #pragma unroll
                for (int i = 0; i < 4; ++i)
                    glds16(vt + voff + (size_t)(n0x + w * 64 + i * 16 + lr) * 4096 + kd + lc,
                           &Vs[p ^ 1][w * 64 + i * 16][0]);
            }
            short8 ap[4], bv[8];
            #pragma unroll
            for (int i = 0; i < 4; ++i)
                ap[i] = *(const short8*)&Pls[wr * 64 + i * 16 + m][vc * 32 + quad * 8];
            #pragma unroll
            for (int j = 0; j < 8; ++j)
                bv[j] = *(const short8*)((const char*)Vs[p] + vof[j]);
            __builtin_amdgcn_s_setprio(1);
            #pragma unroll
            for (int i = 0; i < 4; ++i)
                #pragma unroll
                for (int j = 0; j < 8; ++j)
                    o[i][j] = __builtin_amdgcn_mfma_f32_16x16x32_bf16(ap[i], bv[j], o[i][j], 0, 0, 0);
            __builtin_amdgcn_s_setprio(0);
            __syncthreads();   // Vs buf p free for vc+2; after vc=7: Pls/Qs free for next kt
        }
    }

    // ---- finalize: lane holds rowsum partial for row i*16+m over its 16 cols;
    //      reduce over the quad axis (2 shuffles), combine col-quarters ----
    #pragma unroll
    for (int i = 0; i < 4; ++i) {
        float l = lsum[i];
        l += __shfl_xor(l, 16);
        l += __shfl_xor(l, 32);
        if (quad == 0) redL[wr * 64 + i * 16 + m][wc] = l;
    }
    __syncthreads();
    #pragma unroll
    for (int i = 0; i < 4; ++i)
        #pragma unroll
        for (int e = 0; e < 4; ++e) {
            const int row = wr * 64 + i * 16 + quad * 4 + e;
            const float inv = 1.0f / (redL[row][0] + redL[row][1] + redL[row][2] + redL[row][3]);
            const int g = b * 4096 + r0 + row;
            #pragma unroll
            for (int j = 0; j < 8; ++j)
                out[(size_t)g * 1024 + n0x + wc * 128 + j * 16 + m] = o[i][j][e] * inv;
        }
}

// ---------------------------------------------------------------------------
extern "C" void kernel_launch(void* const* d_in, const int* in_sizes, int n_in,
                              void* d_out, int out_size, void* d_ws, size_t ws_size,
                              hipStream_t stream)
{
    const float* x    = (const float*)d_in[0];
    const float* W    = (const float*)d_in[1];
    const float* bias = (const float*)d_in[2];
    float* out = (float*)d_out;

    const size_t SZQ  = (size_t)4 * 4096 * 1024 * 2;     // 32 MiB each
    const size_t SZWT = (size_t)3072 * 1024 * 2;         // 6 MiB
    const size_t SZXB = (size_t)4 * 4096 * 1024 * 2;     // 32 MiB (bf16 x)
    const size_t NEED  = 3 * SZQ + SZWT;
    const size_t NEED2 = NEED + SZXB;
    if (ws_size < NEED) return;

    ushort_t* q  = (ushort_t*)d_ws;
    ushort_t* k  = (ushort_t*)((char*)d_ws + SZQ);
    ushort_t* vt = (ushort_t*)((char*)d_ws + 2 * SZQ);
    ushort_t* Wt = (ushort_t*)((char*)d_ws + 3 * SZQ);
    ushort_t* xb = (ushort_t*)((char*)d_ws + NEED);

    wt_kernel <<<dim3(16, 48),   256, 0, stream>>>(W, Wt);
    if (ws_size >= NEED2) {
        xcvt      <<<dim3(8192),    256, 0, stream>>>(x, xb);
        qkv_mfma2 <<<dim3(24, 128), 256, 0, stream>>>(xb, Wt, bias, q, k, vt);
    } else {
        qkv_mfma  <<<dim3(24, 128), 256, 0, stream>>>(x, Wt, bias, q, k, vt);
    }
    fused_attn<<<dim3(256), 512, 0, stream>>>(q, k, vt, out);
}